// Round 8
// baseline (183.344 us; speedup 1.0000x reference)
//
#include <hip/hip_runtime.h>
#include <hip/hip_bf16.h>
#include <math.h>

// CrossGeometricStructureEmbedding, round 8.
// R7 audit: per-CU pipe work is MFMA 65k cyc, LDS ~61k, VALU ~68k out of a
// 179k budget — three different pipes each ~37%; limiter is concurrency
// (reg-resident W => 2 waves/SIMD). R8 frees the registers: B streams from
// L2 with a 3-slot rotating prefetch (2 ks-steps/batch, issued 2 batches
// ahead; first batches issued BEFORE the fill so fill+barrier hide them).
// dms dropped (phases interleaved (p,d),(p,a); dmx carried in 2 regs).
// Single-buffer E, LDS ~35 KB; regs ~150 under (256,3)=170 cap (demand
// below cap — the R3/R4 spill rule). Grid 1024 (P_PTS=4): 3 blocks/CU
// resident, cross-block overlap covers the fill->gemm serialization.

typedef __attribute__((ext_vector_type(8))) short short8;
typedef __attribute__((ext_vector_type(16))) float f32x16;
typedef __attribute__((ext_vector_type(4))) unsigned int uint4v;

#define HH 256
#define P_PTS 4
#define NPTS 4096

__device__ __forceinline__ unsigned short f2bf(float f) {
    union { float f; unsigned int u; } v; v.f = f;
    unsigned int r = v.u + 0x7fffu + ((v.u >> 16) & 1u);  // RNE
    return (unsigned short)(r >> 16);
}

__device__ __forceinline__ unsigned int pack_sc(float s, float c) {
    union { __hip_bfloat162 h; unsigned int u; } v;
    v.h = __float22bfloat162_rn(make_float2(s, c));  // low = sin, high = cos
    return v.u;
}

__global__ __launch_bounds__(256)
void prep_w_kernel(const float* __restrict__ Wa, const float* __restrict__ Wd,
                   unsigned short* __restrict__ wbf) {
    int i = blockIdx.x * 256 + threadIdx.x;
    if (i < HH * HH) {
        wbf[i] = f2bf(Wd[i]);             // [0, 65536): Wd bf16
        wbf[HH * HH + i] = f2bf(Wa[i]);   // [65536, 131072): Wa bf16
    }
}

// E chunk addressing: 16B chunks (8 shorts), 32 per 256-short row.
// chunk ch of row r lives at shorts offset r*256 + (((ch ^ (r&7)) & 31) << 3).
__device__ __forceinline__ int eoff(int r, int ch) {
    return r * HH + (((ch ^ (r & 7)) & 31) << 3);
}

__global__ __launch_bounds__(256, 3)
void cgse_main(const float* __restrict__ points,
               const float* __restrict__ anchors,
               const unsigned short* __restrict__ wbf,
               const float* __restrict__ ba,
               const float* __restrict__ bd,
               float* __restrict__ out) {
    __shared__ __align__(16) unsigned short E[64 * HH];   // 32 KB single buf
    __shared__ float xsd[P_PTS][64], xsa[P_PTS][64];      // 2 KB
    __shared__ float anch[192];

    const int tid = threadIdx.x;
    const int wave = tid >> 6, lane = tid & 63;
    const int l5 = lane & 31, half = lane >> 5;
    const int base = blockIdx.x * P_PTS;

    // ---- anchors, then geometry: 4 points x 64 anchors = 256 tasks
    if (tid < 192) anch[tid] = anchors[tid];
    __syncthreads();
    {
        const int pt = wave, k = lane, k2 = (k + 1) & 63;  // roll(-1)
        const int pn = base + pt;
        const float px = points[pn * 3 + 0], py = points[pn * 3 + 1], pz = points[pn * 3 + 2];
        const float r1x = px - anch[k * 3 + 0];
        const float r1y = py - anch[k * 3 + 1];
        const float r1z = pz - anch[k * 3 + 2];
        const float r2x = px - anch[k2 * 3 + 0];
        const float r2y = py - anch[k2 * 3 + 1];
        const float r2z = pz - anch[k2 * 3 + 2];
        xsd[pt][k] = sqrtf(r1x * r1x + r1y * r1y + r1z * r1z) * 5.0f;  // /SIGMA_D
        const float cx = r1y * r2z - r1z * r2y;
        const float cy = r1z * r2x - r1x * r2z;
        const float cz = r1x * r2y - r1y * r2x;
        const float sv = sqrtf(cx * cx + cy * cy + cz * cz);
        const float cv = r1x * r2x + r1y * r2y + r1z * r2z;
        xsa[pt][k] = atan2f(sv, cv) * 3.8197186342054885f;  // *180/(15*pi)
    }

    float bias[2];
    #pragma unroll
    for (int nt = 0; nt < 2; ++nt) {
        const int c = wave * 64 + nt * 32 + l5;
        bias[nt] = ba[c] + bd[c];
    }

    // fill constants (R7-validated): omega_i = x * rho^i / 2pi, rho=1e4^(-1/128)
    const float cw = 0.15915494309189535f * __expf(-(float)wave * 2.302585092994046f);
    const float DC[8] = {1.0f, 0.7498942093324559f, 0.5623413251903491f,
                         0.4216965034285822f, 0.31622776601683794f,
                         0.23713737056616552f, 0.1778279410038923f,
                         0.13335214321633242f};

    // fill one 16B chunk: row = lane, chunk col = 8*wave + c
    auto fill_chunk = [&](int c, float xr) {
        const float t0 = xr * DC[c];
        const float t[4] = {t0, t0 * 0.9305720409297085f,
                            t0 * 0.8659643233600653f, t0 * 0.8058421877614819f};
        uint4v w;
        #pragma unroll
        for (int j = 0; j < 4; ++j) {
            const float f = t[j] - floorf(t[j]);  // revolutions
            w[j] = pack_sc(__builtin_amdgcn_sinf(f), __builtin_amdgcn_cosf(f));
        }
        *(uint4v*)&E[eoff(lane, 8 * wave + c)] = w;
    };

    // B batch loader: 2 ks-steps x 2 nt = 4 frags (16 regs). wb points at this
    // lane's slice: row (wave*64 + l5), k-offset half*8; nt offset 32 rows.
    auto loadB2 = [&](short8* dst, const unsigned short* wb, int ksp) {
        #pragma unroll
        for (int i = 0; i < 2; ++i) {
            dst[i * 2 + 0] = *(const short8*)(wb + (ksp + i) * 16);
            dst[i * 2 + 1] = *(const short8*)(wb + 32 * HH + (ksp + i) * 16);
        }
    };

    const unsigned short* wbase = wbf + (wave * 64 + l5) * HH + half * 8;

    float dmx[2] = {0.f, 0.f};
    __syncthreads();  // xs ready

    // phases: ph = 2q + type; type 0 = d (Wd), 1 = a (Wa)
    #pragma unroll 1
    for (int ph = 0; ph < 2 * P_PTS; ++ph) {
        const int q = ph >> 1, type = ph & 1;
        const unsigned short* wb = wbase + type * (HH * HH);

        // issue first two B batches (ks 0-3); they land during fill+barrier
        short8 B[3][4];
        loadB2(B[0], wb, 0);
        loadB2(B[1], wb, 2);

        // ---- fill E with this phase's embedding
        {
            const float xr = (type ? xsa[q][lane] : xsd[q][lane]) * cw;
            #pragma unroll
            for (int c = 0; c < 8; ++c) fill_chunk(c, xr);
        }
        __syncthreads();  // E ready

        f32x16 acc[2][2];
        #pragma unroll
        for (int mt = 0; mt < 2; ++mt)
            #pragma unroll
            for (int nt = 0; nt < 2; ++nt)
                #pragma unroll
                for (int r = 0; r < 16; ++r) acc[mt][nt][r] = 0.f;

        #pragma unroll
        for (int s = 0; s < 8; ++s) {          // batch s covers ks = 2s, 2s+1
            if (s < 6) loadB2(B[(s + 2) % 3], wb, (s + 2) * 2);
            const short8* bc = B[s % 3];
            #pragma unroll
            for (int i = 0; i < 2; ++i) {
                const int ks = 2 * s + i;
                #pragma unroll
                for (int mt = 0; mt < 2; ++mt) {
                    const short8 afr = *(const short8*)
                        &E[eoff(mt * 32 + l5, 2 * ks + half)];
                    acc[mt][0] = __builtin_amdgcn_mfma_f32_32x32x16_bf16(
                        afr, bc[i * 2 + 0], acc[mt][0], 0, 0, 0);
                    acc[mt][1] = __builtin_amdgcn_mfma_f32_32x32x16_bf16(
                        afr, bc[i * 2 + 1], acc[mt][1], 0, 0, 0);
                }
            }
        }
        __syncthreads();  // E consumed by all waves; next fill may proceed

        // epilogue: max over 64 anchors (C layout: col = l5 per nt tile;
        // 2 mt x 16 regs cover 32 rows, shfl_down(32) merges lane halves)
        #pragma unroll
        for (int nt = 0; nt < 2; ++nt) {
            float m = acc[0][nt][0];
            #pragma unroll
            for (int r = 1; r < 16; ++r) m = fmaxf(m, acc[0][nt][r]);
            #pragma unroll
            for (int r = 0; r < 16; ++r) m = fmaxf(m, acc[1][nt][r]);
            m = fmaxf(m, __shfl_down(m, 32));
            if (type == 0) {
                dmx[nt] = m;  // hold d-max in regs until the a-phase
            } else if (lane < 32) {
                const int col = wave * 64 + nt * 32 + l5;
                out[(base + q) * HH + col] = m + dmx[nt] + bias[nt];
            }
        }
    }
}

extern "C" void kernel_launch(void* const* d_in, const int* in_sizes, int n_in,
                              void* d_out, int out_size, void* d_ws, size_t ws_size,
                              hipStream_t stream) {
    const float* points  = (const float*)d_in[0];
    const float* anchors = (const float*)d_in[1];
    // d_in[2] = cor_score: unused by the reference
    const float* Wa = (const float*)d_in[3];
    const float* ba = (const float*)d_in[4];
    const float* Wd = (const float*)d_in[5];
    const float* bd = (const float*)d_in[6];

    unsigned short* wbf = (unsigned short*)d_ws;  // 256 KB: Wd|Wa bf16

    hipLaunchKernelGGL(prep_w_kernel, dim3(256), dim3(256), 0, stream, Wa, Wd, wbf);
    hipLaunchKernelGGL(cgse_main, dim3(NPTS / P_PTS), dim3(256), 0, stream,
                       points, anchors, wbf, ba, bd, (float*)d_out);
}

// Round 9
// 172.828 us; speedup vs baseline: 1.0608x; 1.0608x over previous
//
#include <hip/hip_runtime.h>
#include <hip/hip_bf16.h>
#include <math.h>

// CrossGeometricStructureEmbedding, round 9: producer/consumer wave roles.
// R8 post-mortem: compiler sinks L2 prefetches (VGPR=64 proved it) => B must
// be register-resident. R7 audit: MFMA 66k / VALU 68k / LDS 77k cyc per CU,
// each ~40% busy — overlap slack. R9: 512-thread blocks, 1 block/CU
// (grid=256): waves 0-3 = GEMM waves (64 cols each, W strip in 128 regs,
// acc in AGPRs, no sincos); waves 4-7 = fill waves (sincos E(t+1) into the
// other dbuf half, no MFMA). Each SIMD hosts one of each => matrix pipe and
// VALU/trans pipe run concurrently (m114). 33 barrier steps: 16 d-phases
// (max -> dms[16][256] LDS), W reload at t=17, 16 a-phases (out = a-max +
// dms + bias). launch_bounds(512,2): cap 256 regs, demand ~222 => no spill.

typedef __attribute__((ext_vector_type(8))) short short8;
typedef __attribute__((ext_vector_type(16))) float f32x16;
typedef __attribute__((ext_vector_type(4))) unsigned int uint4v;

#define HH 256
#define P_PTS 16
#define NPTS 4096

__device__ __forceinline__ unsigned short f2bf(float f) {
    union { float f; unsigned int u; } v; v.f = f;
    unsigned int r = v.u + 0x7fffu + ((v.u >> 16) & 1u);  // RNE
    return (unsigned short)(r >> 16);
}

__device__ __forceinline__ unsigned int pack_sc(float s, float c) {
    union { __hip_bfloat162 h; unsigned int u; } v;
    v.h = __float22bfloat162_rn(make_float2(s, c));  // low = sin, high = cos
    return v.u;
}

__global__ __launch_bounds__(256)
void prep_w_kernel(const float* __restrict__ Wa, const float* __restrict__ Wd,
                   unsigned short* __restrict__ wbf) {
    int i = blockIdx.x * 256 + threadIdx.x;
    if (i < HH * HH) {
        wbf[i] = f2bf(Wd[i]);             // [0, 65536): Wd bf16
        wbf[HH * HH + i] = f2bf(Wa[i]);   // [65536, 131072): Wa bf16
    }
}

// E chunk addressing (R5/R7-validated xor swizzle): 16B chunks, 32/row.
__device__ __forceinline__ int eoff(int r, int ch) {
    return r * HH + (((ch ^ (r & 7)) & 31) << 3);
}

__global__ __launch_bounds__(512, 2)
void cgse_main(const float* __restrict__ points,
               const float* __restrict__ anchors,
               const unsigned short* __restrict__ wbf,
               const float* __restrict__ ba,
               const float* __restrict__ bd,
               float* __restrict__ out) {
    __shared__ __align__(16) unsigned short E[2][64 * HH];  // 64 KB dbuf
    __shared__ float dms[P_PTS][HH];                        // 16 KB d-maxes
    __shared__ float xsd[P_PTS][64], xsa[P_PTS][64];        // 8 KB
    __shared__ float anch[192];

    const int tid = threadIdx.x;
    const int wave = tid >> 6, lane = tid & 63;
    const int l5 = lane & 31, half = lane >> 5;
    const int base = blockIdx.x * P_PTS;

    // ---- anchors + geometry for 16 points (1024 tasks / 512 threads)
    if (tid < 192) anch[tid] = anchors[tid];
    __syncthreads();
    #pragma unroll
    for (int rep = 0; rep < 2; ++rep) {
        const int task = rep * 512 + tid;
        const int pt = task >> 6, k = task & 63, k2 = (k + 1) & 63;
        const int pn = base + pt;
        const float px = points[pn * 3 + 0], py = points[pn * 3 + 1], pz = points[pn * 3 + 2];
        const float r1x = px - anch[k * 3 + 0];
        const float r1y = py - anch[k * 3 + 1];
        const float r1z = pz - anch[k * 3 + 2];
        const float r2x = px - anch[k2 * 3 + 0];
        const float r2y = py - anch[k2 * 3 + 1];
        const float r2z = pz - anch[k2 * 3 + 2];
        xsd[pt][k] = sqrtf(r1x * r1x + r1y * r1y + r1z * r1z) * 5.0f;  // /SIGMA_D
        const float cx = r1y * r2z - r1z * r2y;
        const float cy = r1z * r2x - r1x * r2z;
        const float cz = r1x * r2y - r1y * r2x;
        const float sv = sqrtf(cx * cx + cy * cy + cz * cz);
        const float cv = r1x * r2x + r1y * r2y + r1z * r2z;
        xsa[pt][k] = atan2f(sv, cv) * 3.8197186342054885f;  // *180/(15*pi)
    }

    if (wave < 4) {
        // ================= GEMM waves: cols [wave*64, wave*64+64) ==========
        float bias[2];
        #pragma unroll
        for (int nt = 0; nt < 2; ++nt)
            bias[nt] = ba[wave * 64 + nt * 32 + l5] + bd[wave * 64 + nt * 32 + l5];

        short8 bw[2][16];
        auto loadW = [&](int t) {
            const unsigned short* wp = wbf + t * (HH * HH);
            #pragma unroll
            for (int nt = 0; nt < 2; ++nt) {
                const unsigned short* wr = wp + (wave * 64 + nt * 32 + l5) * HH + half * 8;
                #pragma unroll
                for (int ks = 0; ks < 16; ++ks)
                    bw[nt][ks] = *(const short8*)(wr + ks * 16);
            }
        };
        loadW(0);
        __syncthreads();  // matches fill waves' pre-loop barrier

        #pragma unroll 1
        for (int t = 0; t <= 32; ++t) {
            if (t > 0) {
                if (t == 17) loadW(1);  // switch to Wa for the a-pass
                const int s = t - 1;                 // phase being consumed
                const unsigned short* Eb = E[s & 1];

                f32x16 acc[2][2];
                #pragma unroll
                for (int mt = 0; mt < 2; ++mt)
                    #pragma unroll
                    for (int nt = 0; nt < 2; ++nt)
                        #pragma unroll
                        for (int r = 0; r < 16; ++r) acc[mt][nt][r] = 0.f;

                #pragma unroll
                for (int ks = 0; ks < 16; ++ks) {
                    #pragma unroll
                    for (int mt = 0; mt < 2; ++mt) {
                        const short8 afr = *(const short8*)
                            &Eb[eoff(mt * 32 + l5, 2 * ks + half)];
                        acc[mt][0] = __builtin_amdgcn_mfma_f32_32x32x16_bf16(
                            afr, bw[0][ks], acc[mt][0], 0, 0, 0);
                        acc[mt][1] = __builtin_amdgcn_mfma_f32_32x32x16_bf16(
                            afr, bw[1][ks], acc[mt][1], 0, 0, 0);
                    }
                }

                const int pt = s & 15;
                #pragma unroll
                for (int nt = 0; nt < 2; ++nt) {
                    float m = acc[0][nt][0];
                    #pragma unroll
                    for (int r = 1; r < 16; ++r) m = fmaxf(m, acc[0][nt][r]);
                    #pragma unroll
                    for (int r = 0; r < 16; ++r) m = fmaxf(m, acc[1][nt][r]);
                    m = fmaxf(m, __shfl_down(m, 32));
                    if (lane < 32) {
                        const int col = wave * 64 + nt * 32 + l5;
                        if (s < 16) dms[pt][col] = m;
                        else out[(base + pt) * HH + col] = m + dms[pt][col] + bias[nt];
                    }
                }
            }
            __syncthreads();
        }
    } else {
        // ================= fill waves: E(t) while gemm consumes E(t-1) =====
        const int fw = wave - 4;
        const float cw = 0.15915494309189535f
                         * __expf(-(float)fw * 2.302585092994046f);
        const float DC[8] = {1.0f, 0.7498942093324559f, 0.5623413251903491f,
                             0.4216965034285822f, 0.31622776601683794f,
                             0.23713737056616552f, 0.1778279410038923f,
                             0.13335214321633242f};
        __syncthreads();  // xs ready (matches gemm waves' pre-loop barrier)

        #pragma unroll 1
        for (int t = 0; t <= 32; ++t) {
            if (t < 32) {
                const int pt = t & 15;
                const float xr = (t < 16 ? xsd[pt][lane] : xsa[pt][lane]) * cw;
                unsigned short* Eb = E[t & 1];
                #pragma unroll
                for (int c = 0; c < 8; ++c) {
                    const float t0 = xr * DC[c];
                    const float tt[4] = {t0, t0 * 0.9305720409297085f,
                                         t0 * 0.8659643233600653f,
                                         t0 * 0.8058421877614819f};
                    uint4v w;
                    #pragma unroll
                    for (int j = 0; j < 4; ++j) {
                        const float f = tt[j] - floorf(tt[j]);  // revolutions
                        w[j] = pack_sc(__builtin_amdgcn_sinf(f),
                                       __builtin_amdgcn_cosf(f));
                    }
                    *(uint4v*)&Eb[eoff(lane, 8 * fw + c)] = w;
                }
            }
            __syncthreads();
        }
    }
}

extern "C" void kernel_launch(void* const* d_in, const int* in_sizes, int n_in,
                              void* d_out, int out_size, void* d_ws, size_t ws_size,
                              hipStream_t stream) {
    const float* points  = (const float*)d_in[0];
    const float* anchors = (const float*)d_in[1];
    // d_in[2] = cor_score: unused by the reference
    const float* Wa = (const float*)d_in[3];
    const float* ba = (const float*)d_in[4];
    const float* Wd = (const float*)d_in[5];
    const float* bd = (const float*)d_in[6];

    unsigned short* wbf = (unsigned short*)d_ws;  // 256 KB: Wd|Wa bf16

    hipLaunchKernelGGL(prep_w_kernel, dim3(256), dim3(256), 0, stream, Wa, Wd, wbf);
    hipLaunchKernelGGL(cgse_main, dim3(NPTS / P_PTS), dim3(512), 0, stream,
                       points, anchors, wbf, ba, bd, (float*)d_out);
}

// Round 10
// 142.644 us; speedup vs baseline: 1.2853x; 1.2116x over previous
//
#include <hip/hip_runtime.h>
#include <hip/hip_bf16.h>
#include <math.h>

// CrossGeometricStructureEmbedding, round 10.
// R9 post-mortem: wave specialization at 1 block/CU = barrier-exposed (22%
// MFMA). Model fix: 32x32x16 MFMA = ~32 cyc/SIMD -> chip floor 66k cyc/SIMD
// = 27.5 us. R10 combines the two proven wins: 3 waves/SIMD (R5) with the
// cheap revolution-sincos + 32x32 MFMA (R6/R7). Fill duplication across the
// 2 col-halves now costs 2x26k = 53k cyc/SIMD < the 66k MFMA wall, so it no
// longer sets the pace. Wave owns 32 cols: bw[16]=64 VGPR + acc 32 => demand
// ~145 under (256,3)=170 cap (R5-validated budget, no spill). Grid = 2 col-
// halves x 1024 pt-groups (P=4) = 2048 blocks -> 3 resident blocks/CU;
// cross-block overlap hides the serial fill->gemm phases (R5-proven).
// Per block: d-pass over 4 pts (max -> dms), reload W, a-pass, store.

typedef __attribute__((ext_vector_type(8))) short short8;
typedef __attribute__((ext_vector_type(16))) float f32x16;
typedef __attribute__((ext_vector_type(4))) unsigned int uint4v;

#define HH 256
#define P_PTS 4
#define NPTS 4096

__device__ __forceinline__ unsigned short f2bf(float f) {
    union { float f; unsigned int u; } v; v.f = f;
    unsigned int r = v.u + 0x7fffu + ((v.u >> 16) & 1u);  // RNE
    return (unsigned short)(r >> 16);
}

__device__ __forceinline__ unsigned int pack_sc(float s, float c) {
    union { __hip_bfloat162 h; unsigned int u; } v;
    v.h = __float22bfloat162_rn(make_float2(s, c));  // low = sin, high = cos
    return v.u;
}

__global__ __launch_bounds__(256)
void prep_w_kernel(const float* __restrict__ Wa, const float* __restrict__ Wd,
                   unsigned short* __restrict__ wbf) {
    int i = blockIdx.x * 256 + threadIdx.x;
    if (i < HH * HH) {
        wbf[i] = f2bf(Wd[i]);             // [0, 65536): Wd bf16
        wbf[HH * HH + i] = f2bf(Wa[i]);   // [65536, 131072): Wa bf16
    }
}

// E chunk addressing (R5/R7-validated xor swizzle): 16B chunks, 32/row.
__device__ __forceinline__ int eoff(int r, int ch) {
    return r * HH + (((ch ^ (r & 7)) & 31) << 3);
}

__global__ __launch_bounds__(256, 3)
void cgse_main(const float* __restrict__ points,
               const float* __restrict__ anchors,
               const unsigned short* __restrict__ wbf,
               const float* __restrict__ ba,
               const float* __restrict__ bd,
               float* __restrict__ out) {
    __shared__ __align__(16) unsigned short E[64 * HH];   // 32 KB single buf
    __shared__ float dms[P_PTS][128];                     // 2 KB d-pass maxes
    __shared__ float xsd[P_PTS][64], xsa[P_PTS][64];      // 2 KB
    __shared__ float anch[192];

    const int tid = threadIdx.x;
    const int wave = tid >> 6, lane = tid & 63;
    const int l5 = lane & 31, half = lane >> 5;
    const int cg = blockIdx.x & 1;               // col-half: cols [cg*128, +128)
    const int base = (blockIdx.x >> 1) * P_PTS;  // point group
    const int colw = cg * 128 + wave * 32;       // this wave's 32-col strip

    // ---- anchors + geometry: 4 points x 64 anchors = 256 tasks, 1/thread
    if (tid < 192) anch[tid] = anchors[tid];
    __syncthreads();
    {
        const int pt = wave, k = lane, k2 = (k + 1) & 63;  // roll(-1)
        const int pn = base + pt;
        const float px = points[pn * 3 + 0], py = points[pn * 3 + 1], pz = points[pn * 3 + 2];
        const float r1x = px - anch[k * 3 + 0];
        const float r1y = py - anch[k * 3 + 1];
        const float r1z = pz - anch[k * 3 + 2];
        const float r2x = px - anch[k2 * 3 + 0];
        const float r2y = py - anch[k2 * 3 + 1];
        const float r2z = pz - anch[k2 * 3 + 2];
        xsd[pt][k] = sqrtf(r1x * r1x + r1y * r1y + r1z * r1z) * 5.0f;  // /SIGMA_D
        const float cx = r1y * r2z - r1z * r2y;
        const float cy = r1z * r2x - r1x * r2z;
        const float cz = r1x * r2y - r1y * r2x;
        const float sv = sqrtf(cx * cx + cy * cy + cz * cz);
        const float cv = r1x * r2x + r1y * r2y + r1z * r2z;
        xsa[pt][k] = atan2f(sv, cv) * 3.8197186342054885f;  // *180/(15*pi)
    }

    const float bias = ba[colw + l5] + bd[colw + l5];

    // fill constants (R6/R7-validated): omega_i = x * rho^i / 2pi
    const float cw = 0.15915494309189535f * __expf(-(float)wave * 2.302585092994046f);
    const float DC[8] = {1.0f, 0.7498942093324559f, 0.5623413251903491f,
                         0.4216965034285822f, 0.31622776601683794f,
                         0.23713737056616552f, 0.1778279410038923f,
                         0.13335214321633242f};

    // W strip for this wave (one type at a time): 16 x short8 = 64 VGPRs
    short8 bw[16];
    auto loadW = [&](int t) {
        const unsigned short* wr = wbf + t * (HH * HH) + (colw + l5) * HH + half * 8;
        #pragma unroll
        for (int ks = 0; ks < 16; ++ks)
            bw[ks] = *(const short8*)(wr + ks * 16);
    };

    loadW(0);
    __syncthreads();  // xs ready

    // 8 phases: 0..3 = d-pass (pt 0..3), 4..7 = a-pass (pt 0..3)
    #pragma unroll 1
    for (int ph = 0; ph < 2 * P_PTS; ++ph) {
        const int pt = ph & (P_PTS - 1);
        const bool dpass = ph < P_PTS;
        if (ph == P_PTS) loadW(1);  // switch to Wa

        // ---- fill E (whole 64x256 tile; 8 chunks per thread)
        {
            const float xr = (dpass ? xsd[pt][lane] : xsa[pt][lane]) * cw;
            #pragma unroll
            for (int c = 0; c < 8; ++c) {
                const float t0 = xr * DC[c];
                const float tt[4] = {t0, t0 * 0.9305720409297085f,
                                     t0 * 0.8659643233600653f,
                                     t0 * 0.8058421877614819f};
                uint4v w;
                #pragma unroll
                for (int j = 0; j < 4; ++j) {
                    const float f = tt[j] - floorf(tt[j]);  // revolutions
                    w[j] = pack_sc(__builtin_amdgcn_sinf(f),
                                   __builtin_amdgcn_cosf(f));
                }
                *(uint4v*)&E[eoff(lane, 8 * wave + c)] = w;
            }
        }
        __syncthreads();  // E ready

        f32x16 acc[2];
        #pragma unroll
        for (int mt = 0; mt < 2; ++mt)
            #pragma unroll
            for (int r = 0; r < 16; ++r) acc[mt][r] = 0.f;

        #pragma unroll
        for (int ks = 0; ks < 16; ++ks) {
            #pragma unroll
            for (int mt = 0; mt < 2; ++mt) {
                const short8 afr = *(const short8*)
                    &E[eoff(mt * 32 + l5, 2 * ks + half)];
                acc[mt] = __builtin_amdgcn_mfma_f32_32x32x16_bf16(
                    afr, bw[ks], acc[mt], 0, 0, 0);
            }
        }

        // epilogue: max over 64 anchors (C: col=l5, rows in regs + lane half)
        float m = acc[0][0];
        #pragma unroll
        for (int r = 1; r < 16; ++r) m = fmaxf(m, acc[0][r]);
        #pragma unroll
        for (int r = 0; r < 16; ++r) m = fmaxf(m, acc[1][r]);
        m = fmaxf(m, __shfl_down(m, 32));
        if (lane < 32) {
            if (dpass) dms[pt][wave * 32 + l5] = m;
            else out[(base + pt) * HH + colw + l5] = m + dms[pt][wave * 32 + l5] + bias;
        }
        __syncthreads();  // E + dms consumed; safe to refill
    }
}

extern "C" void kernel_launch(void* const* d_in, const int* in_sizes, int n_in,
                              void* d_out, int out_size, void* d_ws, size_t ws_size,
                              hipStream_t stream) {
    const float* points  = (const float*)d_in[0];
    const float* anchors = (const float*)d_in[1];
    // d_in[2] = cor_score: unused by the reference
    const float* Wa = (const float*)d_in[3];
    const float* ba = (const float*)d_in[4];
    const float* Wd = (const float*)d_in[5];
    const float* bd = (const float*)d_in[6];

    unsigned short* wbf = (unsigned short*)d_ws;  // 256 KB: Wd|Wa bf16

    hipLaunchKernelGGL(prep_w_kernel, dim3(256), dim3(256), 0, stream, Wa, Wd, wbf);
    hipLaunchKernelGGL(cgse_main, dim3(2 * (NPTS / P_PTS)), dim3(256), 0, stream,
                       points, anchors, wbf, ba, bd, (float*)d_out);
}